// Round 10
// baseline (194.803 us; speedup 1.0000x reference)
//
#include <hip/hip_runtime.h>
#include <math.h>

#define ALPHA 0.2f
#define BETA 1.0f
#define EPSV 1e-8f
#define LOG2E 1.4426950408889634f
#define LN2 0.6931471805599453f

#define BATCH 4096
#define RR 18
#define KT 17            // R-1 targets per row
#define DD 256
#define NTGT (BATCH*KT)  // 69632 total targets
#define NTILE (NTGT/32)  // 2176 tiles of 32 targets
#define TILE_BYTES (32*DD) // 8192 fp8 bytes per tile, fragment-ordered

#define AG 64            // anchor groups of 64 (one wave each)
#define NSPLIT 64        // N-dimension splits (grid 4096 -> 4 waves/SIMD)
#define TPS (NTILE/NSPLIT) // 34 tiles per slice
// grid = AG*NSPLIT = 4096 one-wave blocks, barrier-free, self-paced.
// VGPR 116 allows 4 waves/SIMD; doubling resident waves tests whether the
// ~30% neither-pipe time (round-2 accounting) is coverable latency.

// Schraudolph fast exp2: 2^d ~= bitcast(u32(d*2^23 + KBIAS)), d<=0.
// v_cvt_u32_f32 saturates negatives to 0 -> free underflow clamp.
#define EXPA 8388608.0f
#define EXPB 1064880320.0f

typedef int   i32x8  __attribute__((ext_vector_type(8)));
typedef float f32x16 __attribute__((ext_vector_type(16)));

__device__ inline int pk8(float a, float b, float c, float d){
  int p = __builtin_amdgcn_cvt_pk_fp8_f32(a, b, 0, false);
  return  __builtin_amdgcn_cvt_pk_fp8_f32(c, d, p, true);
}

__device__ inline float fmax3(float a, float b, float c){
  return fmaxf(fmaxf(a, b), c);   // clang fuses to v_max3_f32
}

__device__ inline float fexp2u(float x, float kc){
  float t = fmaf(x, EXPA, kc);
  unsigned u;
  asm("v_cvt_u32_f32 %0, %1" : "=v"(u) : "v"(t));   // saturating: t<0 -> 0
  return __uint_as_float(u);
}

// tbf8 fragment layout (fp8 e4m3): target t -> tile = t>>5, m = t&31.
// K split: ki=k>>6 (4), hf=(k>>5)&1, w=(k>>4)&1.
// byte addr = tile*8192 + ki*2048 + w*1024 + hf*512 + m*16.
// Gemm lane l (m=l&31, half=l>>5) loads slot (half,m) of regions (ki,0),(ki,1)
// -> 1KB contiguous per (ki,w) across the wave: perfectly coalesced dwordx4.

// ---------------- Kernel 1: convert->fp8 + KL + diag -------------------------
__global__ __launch_bounds__(256) void prep_kernel(
    const float* __restrict__ feat, const float* __restrict__ scores,
    const float* __restrict__ lscale,
    unsigned char* __restrict__ abf8, unsigned char* __restrict__ tbf8,
    float* __restrict__ diag, float* __restrict__ klarr,
    float* __restrict__ out){
  __shared__ float csh[KT];
  __shared__ uint4 fsh[16][KT];   // fp8 fragments staged for coalesced writeout
  int b = blockIdx.x, tid = threadIdx.x;
  int grp = tid >> 4, j = tid & 15;
  const float* fb = feat + (size_t)b * RR * DD;
  float s2 = lscale[0] * LOG2E;

  if (b == 0 && tid == 0) out[0] = 0.f;   // accumulator for fused final reduce

  // anchor: each lane loads its 16 k-values (same across groups -> L1 broadcast)
  float4 a0 = ((const float4*)fb)[j*4+0];
  float4 a1 = ((const float4*)fb)[j*4+1];
  float4 a2 = ((const float4*)fb)[j*4+2];
  float4 a3 = ((const float4*)fb)[j*4+3];
  float asq = (a0.x*a0.x+a0.y*a0.y+a0.z*a0.z+a0.w*a0.w)
            + (a1.x*a1.x+a1.y*a1.y+a1.z*a1.z+a1.w*a1.w)
            + (a2.x*a2.x+a2.y*a2.y+a2.z*a2.z+a2.w*a2.w)
            + (a3.x*a3.x+a3.y*a3.y+a3.z*a3.z+a3.w*a3.w);
  #pragma unroll
  for (int off=1; off<16; off<<=1) asq += __shfl_xor(asq, off);
  float an = fmaxf(sqrtf(asq), EPSV);

  if (tid < 16){   // anchor fp8 out (scaled into log2 domain), 16 B per lane
    uint4 v = make_uint4(
      (unsigned)pk8(a0.x*s2,a0.y*s2,a0.z*s2,a0.w*s2),
      (unsigned)pk8(a1.x*s2,a1.y*s2,a1.z*s2,a1.w*s2),
      (unsigned)pk8(a2.x*s2,a2.y*s2,a2.z*s2,a2.w*s2),
      (unsigned)pk8(a3.x*s2,a3.y*s2,a3.z*s2,a3.w*s2));
    *(uint4*)(abf8 + (size_t)b*DD + j*16) = v;
  }

  for (int kr = grp+1; kr <= KT; kr += 16){
    const float4* tp = (const float4*)(fb + (size_t)kr*DD) + j*4;
    float4 t0=tp[0], t1=tp[1], t2=tp[2], t3=tp[3];
    // fp8 fragment: lane j holds k in [j*16, j*16+16) -> stage in LDS
    uint4 v = make_uint4(
      (unsigned)pk8(t0.x,t0.y,t0.z,t0.w), (unsigned)pk8(t1.x,t1.y,t1.z,t1.w),
      (unsigned)pk8(t2.x,t2.y,t2.z,t2.w), (unsigned)pk8(t3.x,t3.y,t3.z,t3.w));
    fsh[j][kr-1] = v;
    float d = (a0.x*t0.x+a0.y*t0.y+a0.z*t0.z+a0.w*t0.w)
            + (a1.x*t1.x+a1.y*t1.y+a1.z*t1.z+a1.w*t1.w)
            + (a2.x*t2.x+a2.y*t2.y+a2.z*t2.z+a2.w*t2.w)
            + (a3.x*t3.x+a3.y*t3.y+a3.z*t3.z+a3.w*t3.w);
    float q = (t0.x*t0.x+t0.y*t0.y+t0.z*t0.z+t0.w*t0.w)
            + (t1.x*t1.x+t1.y*t1.y+t1.z*t1.z+t1.w*t1.w)
            + (t2.x*t2.x+t2.y*t2.y+t2.z*t2.z+t2.w*t2.w)
            + (t3.x*t3.x+t3.y*t3.y+t3.z*t3.z+t3.w*t3.w);
    #pragma unroll
    for (int off=1; off<16; off<<=1){ d += __shfl_xor(d,off); q += __shfl_xor(q,off); }
    if (j == 0){
      csh[kr-1] = d / (an * fmaxf(sqrtf(q), EPSV));
      if (kr == 1) diag[b] = d;
    }
  }
  __syncthreads();

  // coalesced tbf8 writeout: 16 j-groups x 17 contiguous 16B slots (272B runs).
  // NOTE: 16*KT = 272 > 256 threads -> MUST grid-stride (round-5/8 bug: a
  // plain `if (tid < 272)` left j-group 15, rows 1..16 unwritten -> absmax 8).
  for (int idx = tid; idx < 16*KT; idx += 256){
    int jj = idx / KT, r = idx % KT;
    uint4 v = fsh[jj][r];
    int t = b*KT + r;
    int tile = t >> 5, m = t & 31;
    int ki = jj >> 2, hf = (jj >> 1) & 1, w = jj & 1;
    *(uint4*)(tbf8 + (size_t)tile*TILE_BYTES + ki*2048 + w*1024 + hf*512 + m*16) = v;
  }

  // KL over KT=17 entries, wave-parallel on wave 0 (lanes >= KT padded)
  if (tid < 64){
    bool act = tid < KT;
    float c  = act ? csh[tid] : -INFINITY;
    float sv = act ? scores[(size_t)b*KT + tid] : -INFINITY;
    float cm = c, sm = sv;
    #pragma unroll
    for (int off=1; off<64; off<<=1){
      cm = fmaxf(cm, __shfl_xor(cm, off));
      sm = fmaxf(sm, __shfl_xor(sm, off));
    }
    float ec = act ? __builtin_amdgcn_exp2f((c -cm)*LOG2E) : 0.f;
    float es = act ? __builtin_amdgcn_exp2f((sv-sm)*LOG2E) : 0.f;
    float cs = ec, ss = es;
    #pragma unroll
    for (int off=1; off<64; off<<=1){
      cs += __shfl_xor(cs, off);
      ss += __shfl_xor(ss, off);
    }
    float lse_c = cm + __logf(cs);
    float lse_s = sm + __logf(ss);
    float kt = 0.f;
    if (act){
      float lq = sv - lse_s;
      float lp = c  - lse_c;
      kt = __builtin_amdgcn_exp2f(lq*LOG2E)*(lq - lp);
    }
    #pragma unroll
    for (int off=1; off<64; off<<=1) kt += __shfl_xor(kt, off);
    if (tid == 0) klarr[b] = kt * (1.0f/KT);
  }
}

// ---------------- Kernel 2: barrier-free MX-fp8 MFMA + online log2-LSE -------
// One wave per block (round-2 skeleton, measured 84.8 us at NSPLIT=32):
// 64 anchors x TPS tiles of 32 targets, A-fragments loaded direct
// global->register, double-buffered two tiles ahead. No LDS, no barriers.
// Epilogue = round-2 scalar form (round-9's packed inline-asm version
// REGRESSED 84.8->95.7: asm blocks defeat the scheduler, T12/m240 lesson).
__global__ __launch_bounds__(64,2) void gemm_lse_kernel(
    const unsigned char* __restrict__ abf8, const unsigned char* __restrict__ tbf8,
    float* __restrict__ part_m, float* __restrict__ part_s){
  const int bid  = blockIdx.x;
  // XCD swizzle (round-robin id%8): 8 ns slices pinned per XCD
  // (8 x 272KB tbf8 + 1MB anchors per XCD L2).
  const int ns   = (bid & 7)*8 + ((bid >> 3) & 7);
  const int ag   = bid >> 6;
  const int lane = threadIdx.x;
  const int l31  = lane & 31;
  const int half = lane >> 5;

  // anchor B-operand frags: n = nt*32+l31, k = ki*64 + half*32 + [0,32)
  i32x8 af[2][4];
  {
    const unsigned char* ab = abf8 + (size_t)ag*64*DD;
    #pragma unroll
    for (int nt=0;nt<2;++nt)
      #pragma unroll
      for (int ki=0;ki<4;++ki){
        const unsigned char* p = ab + (size_t)(nt*32+l31)*DD + ki*64 + half*32;
        uint4* h = (uint4*)&af[nt][ki];
        h[0] = *(const uint4*)p;
        h[1] = *(const uint4*)(p+16);
      }
  }

  const unsigned char* gbase =
      tbf8 + (size_t)(ns*TPS)*TILE_BYTES + half*512 + l31*16;

  i32x8 ta[4], tb[4];
  auto ld = [&](int tt, i32x8 tf[4]){
    const unsigned char* p = gbase + (size_t)tt*TILE_BYTES;
    #pragma unroll
    for (int ki=0;ki<4;++ki){
      uint4* h = (uint4*)&tf[ki];
      h[0] = *(const uint4*)(p + ki*2048);
      h[1] = *(const uint4*)(p + ki*2048 + 1024);
    }
  };

  float run_m[2] = {-INFINITY,-INFINITY};
  float run_s[2] = {0.f,0.f};
  f32x16 acc[2];
  const f32x16 vzero = (f32x16)(0.f);

  auto mfma_tile = [&](i32x8 tf[4]){
    __builtin_amdgcn_s_setprio(1);
    acc[0] = __builtin_amdgcn_mfma_scale_f32_32x32x64_f8f6f4(
                 tf[0], af[0][0], vzero, 0,0, 0,127, 0,127);
    acc[1] = __builtin_amdgcn_mfma_scale_f32_32x32x64_f8f6f4(
                 tf[0], af[1][0], vzero, 0,0, 0,127, 0,127);
    #pragma unroll
    for (int ki=1;ki<4;++ki){
      acc[0] = __builtin_amdgcn_mfma_scale_f32_32x32x64_f8f6f4(
                   tf[ki], af[0][ki], acc[0], 0,0, 0,127, 0,127);
      acc[1] = __builtin_amdgcn_mfma_scale_f32_32x32x64_f8f6f4(
                   tf[ki], af[1][ki], acc[1], 0,0, 0,127, 0,127);
    }
    __builtin_amdgcn_s_setprio(0);
  };

  auto epilogue = [&](){
    #pragma unroll
    for (int nt=0;nt<2;++nt){
      f32x16 t = acc[nt];
      float x0 = fmax3(t[0], t[1], t[2]);
      float x1 = fmax3(t[3], t[4], t[5]);
      float x2 = fmax3(t[6], t[7], t[8]);
      float x3 = fmax3(t[9], t[10], t[11]);
      float x4 = fmax3(t[12], t[13], t[14]);
      float mx = fmaxf(fmax3(x0,x1,x2), fmax3(x3,x4,t[15]));

      float kc = fmaf(mx, -EXPA, EXPB);   // fold -mx into Schraudolph bias
      float s0=0.f, s1=0.f, s2=0.f, s3=0.f;
      #pragma unroll
      for (int r=0;r<16;r+=4){
        s0 += fexp2u(t[r  ],kc);
        s1 += fexp2u(t[r+1],kc);
        s2 += fexp2u(t[r+2],kc);
        s3 += fexp2u(t[r+3],kc);
      }
      float sh = (s0+s1)+(s2+s3);

      float nm = fmaxf(run_m[nt], mx);
      run_s[nt] = run_s[nt]*__builtin_amdgcn_exp2f(run_m[nt]-nm)
                + sh*__builtin_amdgcn_exp2f(mx-nm);
      run_m[nt] = nm;
    }
  };

  ld(0, ta);
  ld(1, tb);
  for (int t=0; t<TPS; t+=2){
    mfma_tile(ta);
    if (t+2 < TPS) ld(t+2, ta);   // issue early: hidden under epilogue+next tile
    epilogue();
    mfma_tile(tb);
    if (t+3 < TPS) ld(t+3, tb);
    epilogue();
  }

  // merge the two half-wave partials (disjoint target rows, same anchor col)
  #pragma unroll
  for (int nt=0;nt<2;++nt){
    float om = __shfl_xor(run_m[nt], 32);
    float os = __shfl_xor(run_s[nt], 32);
    float nm = fmaxf(run_m[nt], om);
    float S  = run_s[nt]*__builtin_amdgcn_exp2f(run_m[nt]-nm)
             + os*__builtin_amdgcn_exp2f(om-nm);
    if (half == 0){
      int gm = ag*64 + nt*32 + l31;
      // transposed layout [ns][gm]: 128B coalesced, no cross-block false sharing
      part_m[(size_t)ns*BATCH + gm] = nm;
      part_s[(size_t)ns*BATCH + gm] = S;
    }
  }
}

// ---------------- Kernel 3: combine partials + fused final reduce ------------
__global__ __launch_bounds__(256) void combine_kernel(
    const float* __restrict__ part_m, const float* __restrict__ part_s,
    const float* __restrict__ diag, const float* __restrict__ klarr,
    const float* __restrict__ lscale, float* __restrict__ out){
  int tid = threadIdx.x;
  int b = blockIdx.x*256 + tid;   // grid 16 x 256 = 4096
  float s = lscale[0];
  float m = -INFINITY, S = 0.f;
  #pragma unroll
  for (int ns=0; ns<NSPLIT; ++ns){
    float pm_ = part_m[(size_t)ns*BATCH + b];
    float ps_ = part_s[(size_t)ns*BATCH + b];
    float nm = fmaxf(m, pm_);
    S = S*__builtin_amdgcn_exp2f(m-nm) + ps_*__builtin_amdgcn_exp2f(pm_-nm);
    m = nm;
  }
  float inf = (m + __log2f(S))*LN2 - s*diag[b];   // back to ln domain
  float c = BETA*klarr[b] + ALPHA*inf;
  #pragma unroll
  for (int off=1; off<64; off<<=1) c += __shfl_xor(c, off);
  if ((tid & 63) == 0) atomicAdd(out, c*(1.0f/BATCH));
}

extern "C" void kernel_launch(void* const* d_in, const int* in_sizes, int n_in,
                              void* d_out, int out_size, void* d_ws, size_t ws_size,
                              hipStream_t stream){
  const float* feat   = (const float*)d_in[0];
  const float* scores = (const float*)d_in[1];
  // d_in[2] row_sizes: shape-only, unused
  const float* lscale = (const float*)d_in[3];

  float* ws     = (float*)d_ws;
  float* diag   = ws;                                   // 4096
  float* klarr  = diag + BATCH;                         // 4096
  float* part_m = klarr + BATCH;                        // 64*4096
  float* part_s = part_m + (size_t)NSPLIT*BATCH;        // 64*4096
  unsigned char* abf8 = (unsigned char*)(part_s + (size_t)NSPLIT*BATCH);
  unsigned char* tbf8 = abf8 + (size_t)BATCH*DD;        // 69632*256 fp8, tile-ordered

  float* outp = (float*)d_out;
  prep_kernel<<<BATCH, 256, 0, stream>>>(feat, scores, lscale, abf8, tbf8,
                                         diag, klarr, outp);
  gemm_lse_kernel<<<AG*NSPLIT, 64, 0, stream>>>(abf8, tbf8, part_m, part_s);
  combine_kernel<<<BATCH/256, 256, 0, stream>>>(part_m, part_s, diag, klarr,
                                                lscale, outp);
}

// Round 11
// 190.165 us; speedup vs baseline: 1.0244x; 1.0244x over previous
//
#include <hip/hip_runtime.h>
#include <math.h>

#define ALPHA 0.2f
#define BETA 1.0f
#define EPSV 1e-8f
#define LOG2E 1.4426950408889634f
#define LN2 0.6931471805599453f

#define BATCH 4096
#define RR 18
#define KT 17            // R-1 targets per row
#define DD 256
#define NTGT (BATCH*KT)  // 69632 total targets
#define NTILE (NTGT/32)  // 2176 tiles of 32 targets
#define TILE_BYTES (32*DD) // 8192 fp8 bytes per tile, fragment-ordered

#define AG 64            // anchor groups of 64 (one wave each)
#define NSPLIT 32        // N-dimension splits
#define TPS (NTILE/NSPLIT) // 68 tiles per slice
// grid = AG*NSPLIT = 2048 one-wave blocks, barrier-free, self-paced.
// 16KB private LDS dbuf/block -> 10 blocks/CU capacity, 8/CU resident (no tail).

// Schraudolph fast exp2: 2^d ~= bitcast(u32(d*2^23 + KBIAS)), d<=0.
// v_cvt_u32_f32 saturates negatives to 0 -> free underflow clamp.
#define EXPA 8388608.0f
#define EXPB 1064880320.0f

typedef int   i32x8  __attribute__((ext_vector_type(8)));
typedef float f32x16 __attribute__((ext_vector_type(16)));

__device__ inline void gl_lds16(const void* g, void* l){
  __builtin_amdgcn_global_load_lds(
      (const __attribute__((address_space(1))) unsigned int*)g,
      (__attribute__((address_space(3))) unsigned int*)l, 16, 0, 0);
}

__device__ inline int pk8(float a, float b, float c, float d){
  int p = __builtin_amdgcn_cvt_pk_fp8_f32(a, b, 0, false);
  return  __builtin_amdgcn_cvt_pk_fp8_f32(c, d, p, true);
}

__device__ inline float fmax3(float a, float b, float c){
  return fmaxf(fmaxf(a, b), c);   // clang fuses to v_max3_f32
}

__device__ inline float fexp2u(float x, float kc){
  float t = fmaf(x, EXPA, kc);
  unsigned u;
  asm("v_cvt_u32_f32 %0, %1" : "=v"(u) : "v"(t));   // saturating: t<0 -> 0
  return __uint_as_float(u);
}

// tbf8 fragment layout (fp8 e4m3): target t -> tile = t>>5, m = t&31.
// K split: ki=k>>6 (4), hf=(k>>5)&1, w=(k>>4)&1.
// byte addr = tile*8192 + ki*2048 + w*1024 + hf*512 + m*16.
// Gemm lane l (m=l&31, half=l>>5) reads slot (half,m) of regions (ki,0),(ki,1)
// -> each ds_read_b128 covers one contiguous 1KB region per wave: conflict-free.

// ---------------- Kernel 1: convert->fp8 + KL + diag -------------------------
__global__ __launch_bounds__(256) void prep_kernel(
    const float* __restrict__ feat, const float* __restrict__ scores,
    const float* __restrict__ lscale,
    unsigned char* __restrict__ abf8, unsigned char* __restrict__ tbf8,
    float* __restrict__ diag, float* __restrict__ klarr,
    float* __restrict__ out){
  __shared__ float csh[KT];
  __shared__ uint4 fsh[16][KT];   // fp8 fragments staged for coalesced writeout
  int b = blockIdx.x, tid = threadIdx.x;
  int grp = tid >> 4, j = tid & 15;
  const float* fb = feat + (size_t)b * RR * DD;
  float s2 = lscale[0] * LOG2E;

  if (b == 0 && tid == 0) out[0] = 0.f;   // accumulator for fused final reduce

  // anchor: each lane loads its 16 k-values (same across groups -> L1 broadcast)
  float4 a0 = ((const float4*)fb)[j*4+0];
  float4 a1 = ((const float4*)fb)[j*4+1];
  float4 a2 = ((const float4*)fb)[j*4+2];
  float4 a3 = ((const float4*)fb)[j*4+3];
  float asq = (a0.x*a0.x+a0.y*a0.y+a0.z*a0.z+a0.w*a0.w)
            + (a1.x*a1.x+a1.y*a1.y+a1.z*a1.z+a1.w*a1.w)
            + (a2.x*a2.x+a2.y*a2.y+a2.z*a2.z+a2.w*a2.w)
            + (a3.x*a3.x+a3.y*a3.y+a3.z*a3.z+a3.w*a3.w);
  #pragma unroll
  for (int off=1; off<16; off<<=1) asq += __shfl_xor(asq, off);
  float an = fmaxf(sqrtf(asq), EPSV);

  if (tid < 16){   // anchor fp8 out (scaled into log2 domain), 16 B per lane
    uint4 v = make_uint4(
      (unsigned)pk8(a0.x*s2,a0.y*s2,a0.z*s2,a0.w*s2),
      (unsigned)pk8(a1.x*s2,a1.y*s2,a1.z*s2,a1.w*s2),
      (unsigned)pk8(a2.x*s2,a2.y*s2,a2.z*s2,a2.w*s2),
      (unsigned)pk8(a3.x*s2,a3.y*s2,a3.z*s2,a3.w*s2));
    *(uint4*)(abf8 + (size_t)b*DD + j*16) = v;
  }

  for (int kr = grp+1; kr <= KT; kr += 16){
    const float4* tp = (const float4*)(fb + (size_t)kr*DD) + j*4;
    float4 t0=tp[0], t1=tp[1], t2=tp[2], t3=tp[3];
    // fp8 fragment: lane j holds k in [j*16, j*16+16) -> stage in LDS
    uint4 v = make_uint4(
      (unsigned)pk8(t0.x,t0.y,t0.z,t0.w), (unsigned)pk8(t1.x,t1.y,t1.z,t1.w),
      (unsigned)pk8(t2.x,t2.y,t2.z,t2.w), (unsigned)pk8(t3.x,t3.y,t3.z,t3.w));
    fsh[j][kr-1] = v;
    float d = (a0.x*t0.x+a0.y*t0.y+a0.z*t0.z+a0.w*t0.w)
            + (a1.x*t1.x+a1.y*t1.y+a1.z*t1.z+a1.w*t1.w)
            + (a2.x*t2.x+a2.y*t2.y+a2.z*t2.z+a2.w*t2.w)
            + (a3.x*t3.x+a3.y*t3.y+a3.z*t3.z+a3.w*t3.w);
    float q = (t0.x*t0.x+t0.y*t0.y+t0.z*t0.z+t0.w*t0.w)
            + (t1.x*t1.x+t1.y*t1.y+t1.z*t1.z+t1.w*t1.w)
            + (t2.x*t2.x+t2.y*t2.y+t2.z*t2.z+t2.w*t2.w)
            + (t3.x*t3.x+t3.y*t3.y+t3.z*t3.z+t3.w*t3.w);
    #pragma unroll
    for (int off=1; off<16; off<<=1){ d += __shfl_xor(d,off); q += __shfl_xor(q,off); }
    if (j == 0){
      csh[kr-1] = d / (an * fmaxf(sqrtf(q), EPSV));
      if (kr == 1) diag[b] = d;
    }
  }
  __syncthreads();

  // coalesced tbf8 writeout: 16 j-groups x 17 contiguous 16B slots (272B runs).
  // NOTE: 16*KT = 272 > 256 threads -> MUST grid-stride (round-5/8 bug: a
  // plain `if (tid < 272)` left j-group 15, rows 1..16 unwritten -> absmax 8).
  for (int idx = tid; idx < 16*KT; idx += 256){
    int jj = idx / KT, r = idx % KT;
    uint4 v = fsh[jj][r];
    int t = b*KT + r;
    int tile = t >> 5, m = t & 31;
    int ki = jj >> 2, hf = (jj >> 1) & 1, w = jj & 1;
    *(uint4*)(tbf8 + (size_t)tile*TILE_BYTES + ki*2048 + w*1024 + hf*512 + m*16) = v;
  }

  // KL over KT=17 entries, wave-parallel on wave 0 (lanes >= KT padded)
  if (tid < 64){
    bool act = tid < KT;
    float c  = act ? csh[tid] : -INFINITY;
    float sv = act ? scores[(size_t)b*KT + tid] : -INFINITY;
    float cm = c, sm = sv;
    #pragma unroll
    for (int off=1; off<64; off<<=1){
      cm = fmaxf(cm, __shfl_xor(cm, off));
      sm = fmaxf(sm, __shfl_xor(sm, off));
    }
    float ec = act ? __builtin_amdgcn_exp2f((c -cm)*LOG2E) : 0.f;
    float es = act ? __builtin_amdgcn_exp2f((sv-sm)*LOG2E) : 0.f;
    float cs = ec, ss = es;
    #pragma unroll
    for (int off=1; off<64; off<<=1){
      cs += __shfl_xor(cs, off);
      ss += __shfl_xor(ss, off);
    }
    float lse_c = cm + __logf(cs);
    float lse_s = sm + __logf(ss);
    float kt = 0.f;
    if (act){
      float lq = sv - lse_s;
      float lp = c  - lse_c;
      kt = __builtin_amdgcn_exp2f(lq*LOG2E)*(lq - lp);
    }
    #pragma unroll
    for (int off=1; off<64; off<<=1) kt += __shfl_xor(kt, off);
    if (tid == 0) klarr[b] = kt * (1.0f/KT);
  }
}

// ---------------- Kernel 2: barrier-free MX-fp8 MFMA + online log2-LSE -------
// One wave per block, PRIVATE 2x8KB LDS double buffer. Tile stream staged via
// global_load_lds (wave-scope DMA: no per-lane 64b VMEM addressing, no VGPR
// round-trip -> kills the ~18us VALU overhead R2/R10 paid vs R4's 39% VALU)
// and consumed via ds_read_b128 with one base reg + immediate offsets.
// No inter-wave sharing -> NO barriers; only per-wave counted vmcnt(8)
// (next tile's 8 DMA ops stay in flight) and lgkmcnt(0) before buffer reuse.
__global__ __launch_bounds__(64,2) void gemm_lse_kernel(
    const unsigned char* __restrict__ abf8, const unsigned char* __restrict__ tbf8,
    float* __restrict__ part_m, float* __restrict__ part_s){
  __shared__ __align__(16) unsigned char Bs[2][TILE_BYTES];   // 16 KB private
  const int bid  = blockIdx.x;
  // XCD swizzle (round-robin id%8): 4 ns slices pinned per XCD.
  const int ns   = (bid & 7)*4 + ((bid >> 3) & 3);
  const int ag   = bid >> 5;
  const int lane = threadIdx.x;
  const int l31  = lane & 31;
  const int half = lane >> 5;

  // anchor B-operand frags: n = nt*32+l31, k = ki*64 + half*32 + [0,32)
  i32x8 af[2][4];
  {
    const unsigned char* ab = abf8 + (size_t)ag*64*DD;
    #pragma unroll
    for (int nt=0;nt<2;++nt)
      #pragma unroll
      for (int ki=0;ki<4;++ki){
        const unsigned char* p = ab + (size_t)(nt*32+l31)*DD + ki*64 + half*32;
        uint4* h = (uint4*)&af[nt][ki];
        h[0] = *(const uint4*)p;
        h[1] = *(const uint4*)(p+16);
      }
  }

  const unsigned char* gt = tbf8 + (size_t)(ns*TPS)*TILE_BYTES + lane*16;
  auto stage = [&](int t, int b){   // 8 x 1KB wave-DMA = one 8KB tile
    const unsigned char* g = gt + (size_t)t*TILE_BYTES;
    #pragma unroll
    for (int j=0;j<8;++j)
      gl_lds16(g + j*1024, &Bs[b][j*1024 + lane*16]);
  };

  const int lbase = half*512 + l31*16;
  float run_m[2] = {-INFINITY,-INFINITY};
  float run_s[2] = {0.f,0.f};
  f32x16 acc[2];
  const f32x16 vzero = (f32x16)(0.f);

  auto mfma_tile = [&](i32x8 tf[4]){
    __builtin_amdgcn_s_setprio(1);
    acc[0] = __builtin_amdgcn_mfma_scale_f32_32x32x64_f8f6f4(
                 tf[0], af[0][0], vzero, 0,0, 0,127, 0,127);
    acc[1] = __builtin_amdgcn_mfma_scale_f32_32x32x64_f8f6f4(
                 tf[0], af[1][0], vzero, 0,0, 0,127, 0,127);
    #pragma unroll
    for (int ki=1;ki<4;++ki){
      acc[0] = __builtin_amdgcn_mfma_scale_f32_32x32x64_f8f6f4(
                   tf[ki], af[0][ki], acc[0], 0,0, 0,127, 0,127);
      acc[1] = __builtin_amdgcn_mfma_scale_f32_32x32x64_f8f6f4(
                   tf[ki], af[1][ki], acc[1], 0,0, 0,127, 0,127);
    }
    __builtin_amdgcn_s_setprio(0);
  };

  auto epilogue = [&](){
    #pragma unroll
    for (int nt=0;nt<2;++nt){
      f32x16 t = acc[nt];
      float x0 = fmax3(t[0], t[1], t[2]);
      float x1 = fmax3(t[3], t[4], t[5]);
      float x2 = fmax3(t[6], t[7], t[8]);
      float x3 = fmax3(t[9], t[10], t[11]);
      float x4 = fmax3(t[12], t[13], t[14]);
      float mx = fmaxf(fmax3(x0,x1,x2), fmax3(x3,x4,t[15]));

      float kc = fmaf(mx, -EXPA, EXPB);   // fold -mx into Schraudolph bias
      float s0=0.f, s1=0.f, s2=0.f, s3=0.f;
      #pragma unroll
      for (int r=0;r<16;r+=4){
        s0 += fexp2u(t[r  ],kc);
        s1 += fexp2u(t[r+1],kc);
        s2 += fexp2u(t[r+2],kc);
        s3 += fexp2u(t[r+3],kc);
      }
      float sh = (s0+s1)+(s2+s3);

      float nm = fmaxf(run_m[nt], mx);
      run_s[nt] = run_s[nt]*__builtin_amdgcn_exp2f(run_m[nt]-nm)
                + sh*__builtin_amdgcn_exp2f(mx-nm);
      run_m[nt] = nm;
    }
  };

  // ds_read one buffer's 8 fragments: single base reg + immediate offsets
  auto tfread0 = [&](i32x8 tf[4]){
    #pragma unroll
    for (int ki=0;ki<4;++ki){
      uint4* h = (uint4*)&tf[ki];
      h[0] = *(const uint4*)(&Bs[0][lbase + ki*2048]);
      h[1] = *(const uint4*)(&Bs[0][lbase + ki*2048 + 1024]);
    }
  };
  auto tfread1 = [&](i32x8 tf[4]){
    #pragma unroll
    for (int ki=0;ki<4;++ki){
      uint4* h = (uint4*)&tf[ki];
      h[0] = *(const uint4*)(&Bs[1][lbase + ki*2048]);
      h[1] = *(const uint4*)(&Bs[1][lbase + ki*2048 + 1024]);
    }
  };

  stage(0, 0);
  stage(1, 1);

  for (int t = 0; t < TPS; t += 2){
    // ---- tile t (buf 0) ----
    // outstanding: tile t (8) + tile t+1 (8) [+ af early, drained first]
    if (t+1 < TPS) asm volatile("s_waitcnt vmcnt(8)" ::: "memory");
    else           asm volatile("s_waitcnt vmcnt(0)" ::: "memory");
    i32x8 tf[4];
    tfread0(tf);
    asm volatile("s_waitcnt lgkmcnt(0)" ::: "memory");  // regs loaded: buf0 reusable
    if (t+2 < TPS) stage(t+2, 0);
    mfma_tile(tf);
    epilogue();
    // ---- tile t+1 (buf 1) ----
    if (t+2 < TPS) asm volatile("s_waitcnt vmcnt(8)" ::: "memory");
    else           asm volatile("s_waitcnt vmcnt(0)" ::: "memory");
    tfread1(tf);
    asm volatile("s_waitcnt lgkmcnt(0)" ::: "memory");  // buf1 reusable
    if (t+3 < TPS) stage(t+3, 1);
    mfma_tile(tf);
    epilogue();
  }

  // merge the two half-wave partials (disjoint target rows, same anchor col)
  #pragma unroll
  for (int nt=0;nt<2;++nt){
    float om = __shfl_xor(run_m[nt], 32);
    float os = __shfl_xor(run_s[nt], 32);
    float nm = fmaxf(run_m[nt], om);
    float S  = run_s[nt]*__builtin_amdgcn_exp2f(run_m[nt]-nm)
             + os*__builtin_amdgcn_exp2f(om-nm);
    if (half == 0){
      int gm = ag*64 + nt*32 + l31;
      // transposed layout [ns][gm]: 128B coalesced, no cross-block false sharing
      part_m[(size_t)ns*BATCH + gm] = nm;
      part_s[(size_t)ns*BATCH + gm] = S;
    }
  }
}

// ---------------- Kernel 3: combine partials + fused final reduce ------------
__global__ __launch_bounds__(256) void combine_kernel(
    const float* __restrict__ part_m, const float* __restrict__ part_s,
    const float* __restrict__ diag, const float* __restrict__ klarr,
    const float* __restrict__ lscale, float* __restrict__ out){
  int tid = threadIdx.x;
  int b = blockIdx.x*256 + tid;   // grid 16 x 256 = 4096
  float s = lscale[0];
  float m = -INFINITY, S = 0.f;
  #pragma unroll
  for (int ns=0; ns<NSPLIT; ++ns){
    float pm_ = part_m[(size_t)ns*BATCH + b];
    float ps_ = part_s[(size_t)ns*BATCH + b];
    float nm = fmaxf(m, pm_);
    S = S*__builtin_amdgcn_exp2f(m-nm) + ps_*__builtin_amdgcn_exp2f(pm_-nm);
    m = nm;
  }
  float inf = (m + __log2f(S))*LN2 - s*diag[b];   // back to ln domain
  float c = BETA*klarr[b] + ALPHA*inf;
  #pragma unroll
  for (int off=1; off<64; off<<=1) c += __shfl_xor(c, off);
  if ((tid & 63) == 0) atomicAdd(out, c*(1.0f/BATCH));
}

extern "C" void kernel_launch(void* const* d_in, const int* in_sizes, int n_in,
                              void* d_out, int out_size, void* d_ws, size_t ws_size,
                              hipStream_t stream){
  const float* feat   = (const float*)d_in[0];
  const float* scores = (const float*)d_in[1];
  // d_in[2] row_sizes: shape-only, unused
  const float* lscale = (const float*)d_in[3];

  float* ws     = (float*)d_ws;
  float* diag   = ws;                                   // 4096
  float* klarr  = diag + BATCH;                         // 4096
  float* part_m = klarr + BATCH;                        // 32*4096
  float* part_s = part_m + (size_t)NSPLIT*BATCH;        // 32*4096
  unsigned char* abf8 = (unsigned char*)(part_s + (size_t)NSPLIT*BATCH);
  unsigned char* tbf8 = abf8 + (size_t)BATCH*DD;        // 69632*256 fp8, tile-ordered

  float* outp = (float*)d_out;
  prep_kernel<<<BATCH, 256, 0, stream>>>(feat, scores, lscale, abf8, tbf8,
                                         diag, klarr, outp);
  gemm_lse_kernel<<<AG*NSPLIT, 64, 0, stream>>>(abf8, tbf8, part_m, part_s);
  combine_kernel<<<BATCH/256, 256, 0, stream>>>(part_m, part_s, diag, klarr,
                                                lscale, outp);
}